// Round 12
// baseline (476.749 us; speedup 1.0000x reference)
//
#include <hip/hip_runtime.h>
#include <stdint.h>

// ScoreMatching: B=2048, D=64, H=512.
// out[b] = 0.5*||s_b||^2 + tr(W4 M3 W3 M2 W2 M1 W1)_b
// div_b = sum_{i,d} m2[i] * C[i,d] * G[i,d]
//   C = W2 @ (M1 .* W1)      [512 x 64]   A-frag = W2 rows,  B-frag = W1T rows
//   G = W3^T @ (M3 .* W4^T)  [512 x 64]   A-frag = W3T rows, B-frag = W4 rows
// R16 changes:
//  - DIAGNOSTIC: div split into 4 dispatches (y0 param, grid (512,2) x4).
//    Each div dispatch ~37us -> forward/convert become visible in rocprof
//    top-5 if they exceed that. Div work/traffic/atomics unchanged.
//  - forward v9 + warm-prefetch: 7 forward variants all land 110-117us ->
//    testing the cold-L2-per-layer-start theory. During layer 2's k-loop each
//    thread touches W3Tf every 128B (1 load/iter, consumed 1 iter later via
//    asm keep-alive -> no stall); W4Tf warmed during layer 3. If each layer
//    start pays L3 fill latency, this removes one of the two big ones.

typedef __attribute__((ext_vector_type(8))) short short8;
typedef __attribute__((ext_vector_type(4))) float f32x4;

union U16x8 {
  uint4 u;
  short8 s;
};

__device__ __forceinline__ uint16_t f2bf(float f) {
  uint32_t u = __float_as_uint(f);
  uint32_t lsb = (u >> 16) & 1u;
  u += 0x7FFFu + lsb;  // round-to-nearest-even
  return (uint16_t)(u >> 16);
}

// async global->LDS, 16B per lane: lane's data lands at lds_base + lane*16.
__device__ __forceinline__ void lds_load16(const uint4* gsrc, uint4* ldst) {
  __builtin_amdgcn_global_load_lds(
      (const __attribute__((address_space(1))) void*)gsrc,
      (__attribute__((address_space(3))) void*)ldst, 16, 0, 0);
}

// ---------------- convert: build swizzled bf16 fragments + fp32 transposes ----------------
// Fragment order (16x16x32 bf16 MFMA): lane = quad*16 + l15 holds 8 contiguous
// bf16 = 16 B; A-frag element (m=l15, k=quad*8+j); B-frag (n=l15, k=quad*8+j).
// A2swz[((r16*16 + kc)*64 + lane)*8 + j] = W2 [r16*16+l15][kc*32+quad*8+j]
// A3swz[  same index                   ] = W3T[r16*16+l15][kc*32+quad*8+j]
// B1swz[((kc*4 + jt)*64 + lane)*8 + j]  = W1T[jt*16+l15 ][kc*32+quad*8+j]
// B4swz[  same index                 ]  = W4 [jt*16+l15 ][kc*32+quad*8+j]
__global__ __launch_bounds__(256) void convert_kernel(
    const float* __restrict__ W1, const float* __restrict__ W2,
    const float* __restrict__ W3, const float* __restrict__ W4,
    uint16_t* __restrict__ A2swz, uint16_t* __restrict__ A3swz,
    uint16_t* __restrict__ B1swz, uint16_t* __restrict__ B4swz,
    float* __restrict__ W2Tf, float* __restrict__ W3Tf,
    float* __restrict__ W1Tf, float* __restrict__ W4Tf) {
  const int i = blockIdx.x * 256 + threadIdx.x;
  if (i < 262144) {  // A2swz
    const int e = i;
    const int f = e >> 3, j = e & 7;
    const int lane = f & 63, fk = f >> 6;
    const int kc = fk & 15, r16 = fk >> 4;
    const int l15 = lane & 15, quad = lane >> 4;
    const int row = r16 * 16 + l15, col = kc * 32 + quad * 8 + j;
    A2swz[e] = f2bf(W2[row * 512 + col]);
  } else if (i < 524288) {  // A3swz (= W3 transposed)
    const int e = i - 262144;
    const int f = e >> 3, j = e & 7;
    const int lane = f & 63, fk = f >> 6;
    const int kc = fk & 15, r16 = fk >> 4;
    const int l15 = lane & 15, quad = lane >> 4;
    const int row = r16 * 16 + l15, col = kc * 32 + quad * 8 + j;
    A3swz[e] = f2bf(W3[col * 512 + row]);
  } else if (i < 557056) {  // B1swz (= W1 transposed)
    const int e = i - 524288;
    const int f = e >> 3, j = e & 7;
    const int lane = f & 63, fk = f >> 6;
    const int kc = fk >> 2, jt = fk & 3;
    const int l15 = lane & 15, quad = lane >> 4;
    const int d = jt * 16 + l15, col = kc * 32 + quad * 8 + j;
    B1swz[e] = f2bf(W1[col * 64 + d]);
  } else if (i < 589824) {  // B4swz (= W4 row-major)
    const int e = i - 557056;
    const int f = e >> 3, j = e & 7;
    const int lane = f & 63, fk = f >> 6;
    const int kc = fk >> 2, jt = fk & 3;
    const int l15 = lane & 15, quad = lane >> 4;
    const int d = jt * 16 + l15, col = kc * 32 + quad * 8 + j;
    B4swz[e] = f2bf(W4[d * 512 + col]);
  } else if (i < 851968) {  // W2Tf [k][j]
    const int e = i - 589824;
    const int k = e >> 9, jj = e & 511;
    W2Tf[e] = W2[jj * 512 + k];
  } else if (i < 1114112) {  // W3Tf [k][j]
    const int e = i - 851968;
    const int k = e >> 9, jj = e & 511;
    W3Tf[e] = W3[jj * 512 + k];
  } else if (i < 1146880) {  // W1Tf [k][j], k<64
    const int e = i - 1114112;
    const int k = e >> 9, jj = e & 511;
    W1Tf[e] = W1[jj * 64 + k];
  } else if (i < 1179648) {  // W4Tf [k][d]
    const int e = i - 1146880;
    const int k = e >> 6, d = e & 63;
    W4Tf[e] = W4[d * 512 + k];
  }
}

// ---------------- forward v9+warm (fp32): K-sliced waves, 4-deep W rotation ----------------
// 512 blocks x 512 threads (8 waves, 2 blocks/CU -> 4 waves/SIMD);
// block = 4 samples. Wave wv owns k-slice [wv*KPW, (wv+1)*KPW).
// Thread owns units {lane+64p, p=0..7} x 4 samples. Per k: 1 broadcast b128
// (h[k][0..3]) + 8 coalesced w-loads + 32 FMA; 4-deep named W/h rotation.
// warm/warmN: per kk-iter q < warmN, touch warm[(q*512+t)*32] (one 128B line
// per 512 threads' stretch) and consume it one iteration later (asm keep-alive)
// -> fire-and-forget L2 warm of the NEXT layer's weights.
__device__ __forceinline__ void fma8x4(float acc[8][4], const float w[8],
                                       const float4 h) {
#pragma unroll
  for (int p = 0; p < 8; ++p) {
    acc[p][0] = fmaf(w[p], h.x, acc[p][0]);
    acc[p][1] = fmaf(w[p], h.y, acc[p][1]);
    acc[p][2] = fmaf(w[p], h.z, acc[p][2]);
    acc[p][3] = fmaf(w[p], h.w, acc[p][3]);
  }
}

template <int KPW>
__device__ __forceinline__ void fwd_layer9(
    const float* __restrict__ WT, const float* __restrict__ bias,
    const float4* __restrict__ src, float4* __restrict__ dst,
    float4 (* __restrict__ pah)[512], uint32_t* __restrict__ mbase,
    int t, int lane, int wv, const float* __restrict__ warm, int warmN) {
  float acc[8][4];
#pragma unroll
  for (int p = 0; p < 8; ++p)
#pragma unroll
    for (int s = 0; s < 4; ++s) acc[p][s] = 0.f;

  const int k0 = wv * KPW;
  const float* Wb = WT + (size_t)k0 * 512 + lane;
  float w0[8], w1[8], w2[8], w3[8];
#pragma unroll
  for (int p = 0; p < 8; ++p) {
    w0[p] = Wb[(size_t)0 * 512 + p * 64];
    w1[p] = Wb[(size_t)1 * 512 + p * 64];
    w2[p] = Wb[(size_t)2 * 512 + p * 64];
    w3[p] = Wb[(size_t)3 * 512 + p * 64];
  }
  float4 h0 = src[k0 + 0], h1 = src[k0 + 1], h2 = src[k0 + 2], h3 = src[k0 + 3];
  float pf = 0.f;  // warm-prefetch rotation register

#pragma unroll 1
  for (int kk = 0; kk < KPW; kk += 4) {
    // buffer q: FMA, then immediately issue its reload for kk+4+q
    // (final iteration over-reads into adjacent workspace/LDS; values unused)
    fma8x4(acc, w0, h0);
    h0 = src[k0 + kk + 4];
#pragma unroll
    for (int p = 0; p < 8; ++p) w0[p] = Wb[(size_t)(kk + 4) * 512 + p * 64];
    fma8x4(acc, w1, h1);
    h1 = src[k0 + kk + 5];
#pragma unroll
    for (int p = 0; p < 8; ++p) w1[p] = Wb[(size_t)(kk + 5) * 512 + p * 64];
    fma8x4(acc, w2, h2);
    h2 = src[k0 + kk + 6];
#pragma unroll
    for (int p = 0; p < 8; ++p) w2[p] = Wb[(size_t)(kk + 6) * 512 + p * 64];
    fma8x4(acc, w3, h3);
    h3 = src[k0 + kk + 7];
#pragma unroll
    for (int p = 0; p < 8; ++p) w3[p] = Wb[(size_t)(kk + 7) * 512 + p * 64];
    // warm-prefetch next layer's weights: consume last iter's value (landed
    // long ago), issue this iter's touch. One 4B load covering 128B stride.
    {
      const int q = kk >> 2;
      if (warm != nullptr && q < warmN) {
        asm volatile("" ::"v"(pf));
        pf = warm[((size_t)q * 512 + t) * 32];
      }
    }
  }
  asm volatile("" ::"v"(pf));  // final consume

  // pairwise partial combine: even waves write, odd waves add (deterministic)
  const int half = wv >> 1;
  if ((wv & 1) == 0) {
#pragma unroll
    for (int p = 0; p < 8; ++p) {
      float4 v;
      v.x = acc[p][0]; v.y = acc[p][1]; v.z = acc[p][2]; v.w = acc[p][3];
      pah[half][p * 64 + lane] = v;
    }
  }
  __syncthreads();
  if (wv & 1) {
#pragma unroll
    for (int p = 0; p < 8; ++p) {
      float4 v = pah[half][p * 64 + lane];
      v.x += acc[p][0]; v.y += acc[p][1]; v.z += acc[p][2]; v.w += acc[p][3];
      pah[half][p * 64 + lane] = v;
    }
  }
  __syncthreads();

  // combine pass: unit u = t
  {
    const int u = t;
    const float4 a0 = pah[0][u], a1 = pah[1][u], a2 = pah[2][u], a3 = pah[3][u];
    const float bj = bias[u];
    float a[4];
    a[0] = ((a0.x + a1.x) + (a2.x + a3.x)) + bj;
    a[1] = ((a0.y + a1.y) + (a2.y + a3.y)) + bj;
    a[2] = ((a0.z + a1.z) + (a2.z + a3.z)) + bj;
    a[3] = ((a0.w + a1.w) + (a2.w + a3.w)) + bj;
#pragma unroll
    for (int s = 0; s < 4; ++s) {
      const unsigned long long bal = __ballot(a[s] > 0.f);
      if (lane == 0) {
        uint2 w2v;
        w2v.x = (uint32_t)bal;
        w2v.y = (uint32_t)(bal >> 32);
        *(uint2*)(mbase + (size_t)s * 16 + 2 * wv) = w2v;
      }
    }
    float4 r;
    r.x = a[0] > 0.f ? a[0] : 0.f;
    r.y = a[1] > 0.f ? a[1] : 0.f;
    r.z = a[2] > 0.f ? a[2] : 0.f;
    r.w = a[3] > 0.f ? a[3] : 0.f;
    dst[u] = r;
  }
  __syncthreads();
}

__global__ __launch_bounds__(512, 4) void forward_kernel(
    const float* __restrict__ x,
    const float* __restrict__ W1Tf, const float* __restrict__ b1,
    const float* __restrict__ W2Tf, const float* __restrict__ b2,
    const float* __restrict__ W3Tf, const float* __restrict__ b3,
    const float* __restrict__ W4Tf, const float* __restrict__ b4,
    uint32_t* __restrict__ m1p, uint32_t* __restrict__ m2p,
    uint32_t* __restrict__ m3p, float* __restrict__ out) {
  // pah declared LAST so k-loop over-prefetch from xs/hU/hV stays in-bounds
  __shared__ float4 xs[64];      // [k] x 4 samples
  __shared__ float4 hU[512];     // [unit] x 4 samples
  __shared__ float4 hV[512];
  __shared__ float4 pah[4][512]; // pairwise partials
  const int t = threadIdx.x;
  const int lane = t & 63, wv = t >> 6;
  const int b0 = blockIdx.x * 4;

  if (t < 256) {
    const int k2 = t >> 2, s2 = t & 3;  // 256 threads cover 4 samples x 64 k
    ((float*)&xs[k2])[s2] = x[(size_t)(b0 + s2) * 64 + k2];
  }
  __syncthreads();

  fwd_layer9<8>(W1Tf, b1, xs, hU, pah, m1p + (size_t)b0 * 16, t, lane, wv,
                W2Tf, 2);
  fwd_layer9<64>(W2Tf, b2, hU, hV, pah, m2p + (size_t)b0 * 16, t, lane, wv,
                 W3Tf, 16);
  fwd_layer9<64>(W3Tf, b3, hV, hU, pah, m3p + (size_t)b0 * 16, t, lane, wv,
                 W4Tf, 2);

  // ---- layer 4 (K=512, D=64) + 0.5*||s||^2 : wave wv owns 64-k slice ----
  {
    const int d = lane;
    const int k0 = wv * 64;
    const float* Wb4 = W4Tf + (size_t)k0 * 64 + d;
    float a4[4] = {0.f, 0.f, 0.f, 0.f};
    float v0 = Wb4[(size_t)0 * 64], v1 = Wb4[(size_t)1 * 64];
    float v2 = Wb4[(size_t)2 * 64], v3 = Wb4[(size_t)3 * 64];
    float4 g0 = hU[k0 + 0], g1 = hU[k0 + 1], g2 = hU[k0 + 2], g3 = hU[k0 + 3];
#pragma unroll 1
    for (int kk = 0; kk < 64; kk += 4) {
      a4[0] = fmaf(v0, g0.x, a4[0]); a4[1] = fmaf(v0, g0.y, a4[1]);
      a4[2] = fmaf(v0, g0.z, a4[2]); a4[3] = fmaf(v0, g0.w, a4[3]);
      g0 = hU[k0 + kk + 4];
      v0 = Wb4[(size_t)(kk + 4) * 64];
      a4[0] = fmaf(v1, g1.x, a4[0]); a4[1] = fmaf(v1, g1.y, a4[1]);
      a4[2] = fmaf(v1, g1.z, a4[2]); a4[3] = fmaf(v1, g1.w, a4[3]);
      g1 = hU[k0 + kk + 5];
      v1 = Wb4[(size_t)(kk + 5) * 64];
      a4[0] = fmaf(v2, g2.x, a4[0]); a4[1] = fmaf(v2, g2.y, a4[1]);
      a4[2] = fmaf(v2, g2.z, a4[2]); a4[3] = fmaf(v2, g2.w, a4[3]);
      g2 = hU[k0 + kk + 6];
      v2 = Wb4[(size_t)(kk + 6) * 64];
      a4[0] = fmaf(v3, g3.x, a4[0]); a4[1] = fmaf(v3, g3.y, a4[1]);
      a4[2] = fmaf(v3, g3.z, a4[2]); a4[3] = fmaf(v3, g3.w, a4[3]);
      g3 = hU[k0 + kk + 7];
      v3 = Wb4[(size_t)(kk + 7) * 64];
    }
    const int half = wv >> 1;
    float4 pv;
    pv.x = a4[0]; pv.y = a4[1]; pv.z = a4[2]; pv.w = a4[3];
    if ((wv & 1) == 0) pah[half][d] = pv;
    __syncthreads();
    if (wv & 1) {
      float4 v = pah[half][d];
      v.x += pv.x; v.y += pv.y; v.z += pv.z; v.w += pv.w;
      pah[half][d] = v;
    }
    __syncthreads();
  }
  if (t < 64) {
    const float4 q0 = pah[0][t], q1 = pah[1][t], q2 = pah[2][t], q3 = pah[3][t];
    const float bj = b4[t];
    float sq[4];
    sq[0] = ((q0.x + q1.x) + (q2.x + q3.x)) + bj;
    sq[1] = ((q0.y + q1.y) + (q2.y + q3.y)) + bj;
    sq[2] = ((q0.z + q1.z) + (q2.z + q3.z)) + bj;
    sq[3] = ((q0.w + q1.w) + (q2.w + q3.w)) + bj;
#pragma unroll
    for (int s = 0; s < 4; ++s) sq[s] *= sq[s];
#pragma unroll
    for (int off = 32; off; off >>= 1) {
      sq[0] += __shfl_down(sq[0], off, 64);
      sq[1] += __shfl_down(sq[1], off, 64);
      sq[2] += __shfl_down(sq[2], off, 64);
      sq[3] += __shfl_down(sq[3], off, 64);
    }
    if (t == 0) {
      out[b0 + 0] = 0.5f * sq[0];
      out[b0 + 1] = 0.5f * sq[1];
      out[b0 + 2] = 0.5f * sq[2];
      out[b0 + 3] = 0.5f * sq[3];
    }
  }
}

// ---------------- divergence v5 (147us stable): C/G wave split, 4 waves/SIMD ----------------
// NOW LAUNCHED AS 4 DISPATCHES (y0 = 0,2,4,6; grid (512,2)) so each dispatch
// is ~37us -> forward/convert become visible in rocprof top-5. Work identical.
// grid (512 sample-quads, 2 row-tiles of 64); block 512 = 8 waves.
// Wave wv: sLoc = wv&3 -> sample g4*4+sLoc; role = (wv<4 ? C : G).
// Staging: per kc, block stages 16 slots (A2 it0-3 | u1 jt0-3 | A3 it0-3 |
// u4 jt0-3); wave wv stages slots wv*2, wv*2+1 (2 global_load_lds). 3 buffers,
// stage kc+2 at top of kc, end-of-kc s_waitcnt vmcnt(2) + raw s_barrier.
// Masks: expand_mask hoisted to LDS (emask); in-loop one broadcast b128 per kc.
// Epilogue: C-waves write accC to LDS (stride-65); G-waves apply m2, reduce.
__device__ __forceinline__ void expand_mask(uint32_t byte8, uint32_t mk[4]) {
#pragma unroll
  for (int i = 0; i < 4; ++i) {
    mk[i] = (((byte8 >> (2 * i)) & 1u) ? 0x0000FFFFu : 0u) |
            (((byte8 >> (2 * i + 1)) & 1u) ? 0xFFFF0000u : 0u);
  }
}

__global__ __launch_bounds__(512, 4) void div_kernel(
    const uint4* __restrict__ A2swz, const uint4* __restrict__ A3swz,
    const uint4* __restrict__ B1swz, const uint4* __restrict__ B4swz,
    const uint32_t* __restrict__ m1p, const uint32_t* __restrict__ m2p,
    const uint32_t* __restrict__ m3p, float* __restrict__ out, int y0) {
  __shared__ uint4 sfrag[3][16][64];   // 48KB: [buf][slot][lane]
  __shared__ uint4 emask[8][16][4];    // 8KB: [wave][kc][quad] expanded masks
  const int t = threadIdx.x;
  const int lane = t & 63, wv = t >> 6;
  const int quad = lane >> 4, l15 = lane & 15;
  const int g4 = blockIdx.x;
  const int yb = y0 + blockIdx.y;
  const int rowB0 = yb * 64;
  const int sLoc = wv & 3;
  const int b = g4 * 4 + sLoc;        // this wave's sample
  const int r16b = yb * 4;            // row-16-tile base
  const bool isC = (wv < 4);

  // staging source base for this wave's 2 slots
  const uint4* sb = (wv < 2) ? A2swz : (wv < 4) ? B1swz : (wv < 6) ? A3swz : B4swz;

  f32x4 acc[4][4];
#pragma unroll
  for (int it = 0; it < 4; ++it)
#pragma unroll
    for (int jt = 0; jt < 4; ++jt) acc[it][jt] = (f32x4){0.f, 0.f, 0.f, 0.f};

  // per-wave expanded-mask precompute: lane -> (kc = lane>>2, qd = lane&3).
  // C-waves use m1, G-waves use m3. Wave-private (in-wave lgkmcnt ordering).
  {
    const uint32_t* mp = (isC ? m1p : m3p) + (size_t)b * 16;
    const int kcl = lane >> 2, qd = lane & 3;
    const uint32_t word = mp[kcl];
    uint32_t mk[4];
    expand_mask((word >> (qd * 8)) & 0xFFu, mk);
    uint4 v;
    v.x = mk[0]; v.y = mk[1]; v.z = mk[2]; v.w = mk[3];
    emask[wv][kcl][qd] = v;
  }

  // stage(buf, kc): wave wv stages slots wv*2, wv*2+1
  auto stage = [&](int sbuf, int kc) {
#pragma unroll
    for (int q = 0; q < 2; ++q) {
      const int sub = (wv & 1) * 2 + q;  // it or jt index
      const size_t off = ((wv & 2) == 0)
          ? ((size_t)((r16b + sub) * 16 + kc) * 64 + lane)   // A2 / A3
          : ((size_t)(kc * 4 + sub) * 64 + lane);            // B1 / B4
      lds_load16(sb + off, &sfrag[sbuf][wv * 2 + q][0]);
    }
  };

  stage(0, 0);
  stage(1, 1);
  __builtin_amdgcn_sched_barrier(0);
  asm volatile("s_waitcnt vmcnt(2)" ::: "memory");  // kc=0 staging complete
  __builtin_amdgcn_s_barrier();
  __builtin_amdgcn_sched_barrier(0);

  const int base = isC ? 0 : 8;

#pragma unroll 1
  for (int kc = 0; kc < 16; ++kc) {
    const int rb = kc % 3;
    if (kc < 14) stage((kc + 2) % 3, kc + 2);  // keep 2 kc in flight

    const uint4 mku = emask[wv][kc][quad];  // broadcast ds_read_b128

    uint4 a[4], u[4];
#pragma unroll
    for (int q = 0; q < 4; ++q) {
      a[q] = sfrag[rb][base + q][lane];
      u[q] = sfrag[rb][base + 4 + q][lane];
    }

    short8 bf[4];
#pragma unroll
    for (int jt = 0; jt < 4; ++jt) {
      U16x8 uu;
      uu.u = u[jt];
      uu.u.x &= mku.x; uu.u.y &= mku.y; uu.u.z &= mku.z; uu.u.w &= mku.w;
      bf[jt] = uu.s;
    }
#pragma unroll
    for (int it = 0; it < 4; ++it) {
      U16x8 ua;
      ua.u = a[it];
      const short8 af = ua.s;
#pragma unroll
      for (int jt = 0; jt < 4; ++jt)
        acc[it][jt] = __builtin_amdgcn_mfma_f32_16x16x32_bf16(af, bf[jt], acc[it][jt], 0, 0, 0);
    }

    // counted wait: kc+1's staging (oldest 2) done; kc+2's 2 stay in flight.
    if (kc < 14) {
      asm volatile("s_waitcnt vmcnt(2)" ::: "memory");
    } else if (kc == 14) {
      asm volatile("s_waitcnt vmcnt(0)" ::: "memory");  // drain last stage
    }
    if (kc < 15) {
      __builtin_amdgcn_s_barrier();
      __builtin_amdgcn_sched_barrier(0);  // no ds_read hoisting above barrier
    }
  }

  // ---- epilogue: exchange C via LDS (2 halves of 32 rows), G applies m2 ----
  // C/D layout: row = it*16 + quad*4 + reg, col = jt*16 + l15.
  __syncthreads();  // all sfrag reads done; safe to overlay
  float* cxf = (float*)&sfrag[0][0][0];  // [sample][32 rows][stride 65]
  float dsum = 0.f;
  const uint32_t* m2w = m2p + (size_t)b * 16;
#pragma unroll
  for (int h = 0; h < 2; ++h) {
    if (isC) {
#pragma unroll
      for (int ith = 0; ith < 2; ++ith)
#pragma unroll
        for (int jt = 0; jt < 4; ++jt) {
          float* crow = &cxf[((size_t)sLoc * 32 + ith * 16 + quad * 4) * 65 +
                             jt * 16 + l15];
          crow[0 * 65] = acc[h * 2 + ith][jt][0];
          crow[1 * 65] = acc[h * 2 + ith][jt][1];
          crow[2 * 65] = acc[h * 2 + ith][jt][2];
          crow[3 * 65] = acc[h * 2 + ith][jt][3];
        }
    }
    __syncthreads();
    if (!isC) {
#pragma unroll
      for (int ith = 0; ith < 2; ++ith) {
        const int it = h * 2 + ith;
        const int rloc = it * 16 + quad * 4;
        const uint32_t md = m2w[(rowB0 + rloc) >> 5];
        const uint32_t bits = (md >> (rloc & 31)) & 0xFu;
        const float w0 = (bits & 1u) ? 1.f : 0.f;
        const float w1 = (bits & 2u) ? 1.f : 0.f;
        const float w2 = (bits & 4u) ? 1.f : 0.f;
        const float w3 = (bits & 8u) ? 1.f : 0.f;
#pragma unroll
        for (int jt = 0; jt < 4; ++jt) {
          const float* crow = &cxf[((size_t)sLoc * 32 + ith * 16 + quad * 4) * 65 +
                                   jt * 16 + l15];
          dsum = fmaf(w0, acc[it][jt][0] * crow[0 * 65], dsum);
          dsum = fmaf(w1, acc[it][jt][1] * crow[1 * 65], dsum);
          dsum = fmaf(w2, acc[it][jt][2] * crow[2 * 65], dsum);
          dsum = fmaf(w3, acc[it][jt][3] * crow[3 * 65], dsum);
        }
      }
    }
    __syncthreads();
  }
  if (!isC) {
#pragma unroll
    for (int off = 32; off; off >>= 1) dsum += __shfl_down(dsum, off, 64);
    if (lane == 0) atomicAdd(out + b, dsum);
  }
}

extern "C" void kernel_launch(void* const* d_in, const int* in_sizes, int n_in,
                              void* d_out, int out_size, void* d_ws, size_t ws_size,
                              hipStream_t stream) {
  const float* x  = (const float*)d_in[0];
  const float* W1 = (const float*)d_in[1];
  const float* b1 = (const float*)d_in[2];
  const float* W2 = (const float*)d_in[3];
  const float* b2 = (const float*)d_in[4];
  const float* W3 = (const float*)d_in[5];
  const float* b3 = (const float*)d_in[6];
  const float* W4 = (const float*)d_in[7];
  const float* b4 = (const float*)d_in[8];
  float* out = (float*)d_out;

  // workspace layout (bytes), total 3,932,160:
  char* ws = (char*)d_ws;
  uint16_t* A2swz = (uint16_t*)(ws + 0);        // 524288
  uint16_t* A3swz = (uint16_t*)(ws + 524288);   // 524288
  uint16_t* B1swz = (uint16_t*)(ws + 1048576);  // 65536
  uint16_t* B4swz = (uint16_t*)(ws + 1114112);  // 65536
  float*    W2Tf  = (float*)(ws + 1179648);     // 1048576
  float*    W3Tf  = (float*)(ws + 2228224);     // 1048576
  float*    W1Tf  = (float*)(ws + 3276800);     // 131072
  float*    W4Tf  = (float*)(ws + 3407872);     // 131072
  uint32_t* m1p   = (uint32_t*)(ws + 3538944);  // 131072 (2048 x 512 bits)
  uint32_t* m2p   = (uint32_t*)(ws + 3670016);  // 131072
  uint32_t* m3p   = (uint32_t*)(ws + 3801088);  // 131072
  if (ws_size < 3932160) return;

  convert_kernel<<<4608, 256, 0, stream>>>(W1, W2, W3, W4,
                                           A2swz, A3swz, B1swz, B4swz,
                                           W2Tf, W3Tf, W1Tf, W4Tf);
  forward_kernel<<<512, 512, 0, stream>>>(x, W1Tf, b1, W2Tf, b2, W3Tf, b3,
                                          W4Tf, b4, m1p, m2p, m3p, out);
  for (int y0 = 0; y0 < 8; y0 += 2) {
    div_kernel<<<dim3(512, 2), 512, 0, stream>>>((const uint4*)A2swz,
                                                 (const uint4*)A3swz,
                                                 (const uint4*)B1swz,
                                                 (const uint4*)B4swz,
                                                 m1p, m2p, m3p, out, y0);
  }
}

// Round 13
// 262.634 us; speedup vs baseline: 1.8153x; 1.8153x over previous
//
#include <hip/hip_runtime.h>
#include <stdint.h>

// ScoreMatching: B=2048, D=64, H=512.
// out[b] = 0.5*||s_b||^2 + tr(W4 M3 W3 M2 W2 M1 W1)_b
// div_b = sum_{i,d} m2[i] * C[i,d] * G[i,d]
//   C = W2 @ (M1 .* W1)      [512 x 64]   A-frag = W2 rows,  B-frag = W1T rows
//   G = W3^T @ (M3 .* W4^T)  [512 x 64]   A-frag = W3T rows, B-frag = W4 rows
// R17 changes:
//  - R12's diagnostic caught it: forward had VGPR_Count=64 with 733MB of
//    scratch-spill WRITE_SIZE (2.8KB/thread) -- the entire ~300us (and likely
//    R11's 116us) was spill round-trip. __launch_bounds__(512,4)'s second arg
//    produced a 64-reg budget; the v9 pipeline needs ~95.
//    Fix: __launch_bounds__(512) + amdgpu_waves_per_eu(4,4) -> 128-reg budget,
//    no spill, same 2 blocks/CU occupancy. Warm-prefetch REMOVED (regression).
//  - div v5 kept as 4 split dispatches (y0; ~37us each) for counter
//    visibility; work identical, overhead ~1us.

typedef __attribute__((ext_vector_type(8))) short short8;
typedef __attribute__((ext_vector_type(4))) float f32x4;

union U16x8 {
  uint4 u;
  short8 s;
};

__device__ __forceinline__ uint16_t f2bf(float f) {
  uint32_t u = __float_as_uint(f);
  uint32_t lsb = (u >> 16) & 1u;
  u += 0x7FFFu + lsb;  // round-to-nearest-even
  return (uint16_t)(u >> 16);
}

// async global->LDS, 16B per lane: lane's data lands at lds_base + lane*16.
__device__ __forceinline__ void lds_load16(const uint4* gsrc, uint4* ldst) {
  __builtin_amdgcn_global_load_lds(
      (const __attribute__((address_space(1))) void*)gsrc,
      (__attribute__((address_space(3))) void*)ldst, 16, 0, 0);
}

// ---------------- convert: build swizzled bf16 fragments + fp32 transposes ----------------
// Fragment order (16x16x32 bf16 MFMA): lane = quad*16 + l15 holds 8 contiguous
// bf16 = 16 B; A-frag element (m=l15, k=quad*8+j); B-frag (n=l15, k=quad*8+j).
// A2swz[((r16*16 + kc)*64 + lane)*8 + j] = W2 [r16*16+l15][kc*32+quad*8+j]
// A3swz[  same index                   ] = W3T[r16*16+l15][kc*32+quad*8+j]
// B1swz[((kc*4 + jt)*64 + lane)*8 + j]  = W1T[jt*16+l15 ][kc*32+quad*8+j]
// B4swz[  same index                 ]  = W4 [jt*16+l15 ][kc*32+quad*8+j]
__global__ __launch_bounds__(256) void convert_kernel(
    const float* __restrict__ W1, const float* __restrict__ W2,
    const float* __restrict__ W3, const float* __restrict__ W4,
    uint16_t* __restrict__ A2swz, uint16_t* __restrict__ A3swz,
    uint16_t* __restrict__ B1swz, uint16_t* __restrict__ B4swz,
    float* __restrict__ W2Tf, float* __restrict__ W3Tf,
    float* __restrict__ W1Tf, float* __restrict__ W4Tf) {
  const int i = blockIdx.x * 256 + threadIdx.x;
  if (i < 262144) {  // A2swz
    const int e = i;
    const int f = e >> 3, j = e & 7;
    const int lane = f & 63, fk = f >> 6;
    const int kc = fk & 15, r16 = fk >> 4;
    const int l15 = lane & 15, quad = lane >> 4;
    const int row = r16 * 16 + l15, col = kc * 32 + quad * 8 + j;
    A2swz[e] = f2bf(W2[row * 512 + col]);
  } else if (i < 524288) {  // A3swz (= W3 transposed)
    const int e = i - 262144;
    const int f = e >> 3, j = e & 7;
    const int lane = f & 63, fk = f >> 6;
    const int kc = fk & 15, r16 = fk >> 4;
    const int l15 = lane & 15, quad = lane >> 4;
    const int row = r16 * 16 + l15, col = kc * 32 + quad * 8 + j;
    A3swz[e] = f2bf(W3[col * 512 + row]);
  } else if (i < 557056) {  // B1swz (= W1 transposed)
    const int e = i - 524288;
    const int f = e >> 3, j = e & 7;
    const int lane = f & 63, fk = f >> 6;
    const int kc = fk >> 2, jt = fk & 3;
    const int l15 = lane & 15, quad = lane >> 4;
    const int d = jt * 16 + l15, col = kc * 32 + quad * 8 + j;
    B1swz[e] = f2bf(W1[col * 64 + d]);
  } else if (i < 589824) {  // B4swz (= W4 row-major)
    const int e = i - 557056;
    const int f = e >> 3, j = e & 7;
    const int lane = f & 63, fk = f >> 6;
    const int kc = fk >> 2, jt = fk & 3;
    const int l15 = lane & 15, quad = lane >> 4;
    const int d = jt * 16 + l15, col = kc * 32 + quad * 8 + j;
    B4swz[e] = f2bf(W4[d * 512 + col]);
  } else if (i < 851968) {  // W2Tf [k][j]
    const int e = i - 589824;
    const int k = e >> 9, jj = e & 511;
    W2Tf[e] = W2[jj * 512 + k];
  } else if (i < 1114112) {  // W3Tf [k][j]
    const int e = i - 851968;
    const int k = e >> 9, jj = e & 511;
    W3Tf[e] = W3[jj * 512 + k];
  } else if (i < 1146880) {  // W1Tf [k][j], k<64
    const int e = i - 1114112;
    const int k = e >> 9, jj = e & 511;
    W1Tf[e] = W1[jj * 64 + k];
  } else if (i < 1179648) {  // W4Tf [k][d]
    const int e = i - 1146880;
    const int k = e >> 6, d = e & 63;
    W4Tf[e] = W4[d * 512 + k];
  }
}

// ---------------- forward v10 (fp32): v9 structure, spill-free reg budget ----------------
// 512 blocks x 512 threads (8 waves); block = 4 samples; amdgpu_waves_per_eu
// (4,4) pins a 128-VGPR budget (2 blocks/CU) so the ~95-reg pipeline fits
// WITHOUT scratch spill (R12: launch_bounds(512,4) yielded a 64-reg budget
// and 733MB of spill writes/dispatch).
// Wave wv owns k-slice [wv*KPW,(wv+1)*KPW). Thread owns units {lane+64p} x
// 4 samples. Per k: 1 broadcast b128 + 8 coalesced w-loads + 32 FMA; 4-deep
// named W/h rotation (reload issued ~48 FMA before next use).
__device__ __forceinline__ void fma8x4(float acc[8][4], const float w[8],
                                       const float4 h) {
#pragma unroll
  for (int p = 0; p < 8; ++p) {
    acc[p][0] = fmaf(w[p], h.x, acc[p][0]);
    acc[p][1] = fmaf(w[p], h.y, acc[p][1]);
    acc[p][2] = fmaf(w[p], h.z, acc[p][2]);
    acc[p][3] = fmaf(w[p], h.w, acc[p][3]);
  }
}

template <int KPW>
__device__ __forceinline__ void fwd_layer9(
    const float* __restrict__ WT, const float* __restrict__ bias,
    const float4* __restrict__ src, float4* __restrict__ dst,
    float4 (* __restrict__ pah)[512], uint32_t* __restrict__ mbase,
    int t, int lane, int wv) {
  float acc[8][4];
#pragma unroll
  for (int p = 0; p < 8; ++p)
#pragma unroll
    for (int s = 0; s < 4; ++s) acc[p][s] = 0.f;

  const int k0 = wv * KPW;
  const float* Wb = WT + (size_t)k0 * 512 + lane;
  float w0[8], w1[8], w2[8], w3[8];
#pragma unroll
  for (int p = 0; p < 8; ++p) {
    w0[p] = Wb[(size_t)0 * 512 + p * 64];
    w1[p] = Wb[(size_t)1 * 512 + p * 64];
    w2[p] = Wb[(size_t)2 * 512 + p * 64];
    w3[p] = Wb[(size_t)3 * 512 + p * 64];
  }
  float4 h0 = src[k0 + 0], h1 = src[k0 + 1], h2 = src[k0 + 2], h3 = src[k0 + 3];

#pragma unroll 1
  for (int kk = 0; kk < KPW; kk += 4) {
    // buffer q: FMA, then immediately issue its reload for kk+4+q
    // (final iteration over-reads into adjacent workspace/LDS; values unused)
    fma8x4(acc, w0, h0);
    h0 = src[k0 + kk + 4];
#pragma unroll
    for (int p = 0; p < 8; ++p) w0[p] = Wb[(size_t)(kk + 4) * 512 + p * 64];
    fma8x4(acc, w1, h1);
    h1 = src[k0 + kk + 5];
#pragma unroll
    for (int p = 0; p < 8; ++p) w1[p] = Wb[(size_t)(kk + 5) * 512 + p * 64];
    fma8x4(acc, w2, h2);
    h2 = src[k0 + kk + 6];
#pragma unroll
    for (int p = 0; p < 8; ++p) w2[p] = Wb[(size_t)(kk + 6) * 512 + p * 64];
    fma8x4(acc, w3, h3);
    h3 = src[k0 + kk + 7];
#pragma unroll
    for (int p = 0; p < 8; ++p) w3[p] = Wb[(size_t)(kk + 7) * 512 + p * 64];
  }

  // pairwise partial combine: even waves write, odd waves add (deterministic)
  const int half = wv >> 1;
  if ((wv & 1) == 0) {
#pragma unroll
    for (int p = 0; p < 8; ++p) {
      float4 v;
      v.x = acc[p][0]; v.y = acc[p][1]; v.z = acc[p][2]; v.w = acc[p][3];
      pah[half][p * 64 + lane] = v;
    }
  }
  __syncthreads();
  if (wv & 1) {
#pragma unroll
    for (int p = 0; p < 8; ++p) {
      float4 v = pah[half][p * 64 + lane];
      v.x += acc[p][0]; v.y += acc[p][1]; v.z += acc[p][2]; v.w += acc[p][3];
      pah[half][p * 64 + lane] = v;
    }
  }
  __syncthreads();

  // combine pass: unit u = t
  {
    const int u = t;
    const float4 a0 = pah[0][u], a1 = pah[1][u], a2 = pah[2][u], a3 = pah[3][u];
    const float bj = bias[u];
    float a[4];
    a[0] = ((a0.x + a1.x) + (a2.x + a3.x)) + bj;
    a[1] = ((a0.y + a1.y) + (a2.y + a3.y)) + bj;
    a[2] = ((a0.z + a1.z) + (a2.z + a3.z)) + bj;
    a[3] = ((a0.w + a1.w) + (a2.w + a3.w)) + bj;
#pragma unroll
    for (int s = 0; s < 4; ++s) {
      const unsigned long long bal = __ballot(a[s] > 0.f);
      if (lane == 0) {
        uint2 w2v;
        w2v.x = (uint32_t)bal;
        w2v.y = (uint32_t)(bal >> 32);
        *(uint2*)(mbase + (size_t)s * 16 + 2 * wv) = w2v;
      }
    }
    float4 r;
    r.x = a[0] > 0.f ? a[0] : 0.f;
    r.y = a[1] > 0.f ? a[1] : 0.f;
    r.z = a[2] > 0.f ? a[2] : 0.f;
    r.w = a[3] > 0.f ? a[3] : 0.f;
    dst[u] = r;
  }
  __syncthreads();
}

__global__ __launch_bounds__(512)
__attribute__((amdgpu_waves_per_eu(4, 4)))
void forward_kernel(
    const float* __restrict__ x,
    const float* __restrict__ W1Tf, const float* __restrict__ b1,
    const float* __restrict__ W2Tf, const float* __restrict__ b2,
    const float* __restrict__ W3Tf, const float* __restrict__ b3,
    const float* __restrict__ W4Tf, const float* __restrict__ b4,
    uint32_t* __restrict__ m1p, uint32_t* __restrict__ m2p,
    uint32_t* __restrict__ m3p, float* __restrict__ out) {
  // pah declared LAST so k-loop over-prefetch from xs/hU/hV stays in-bounds
  __shared__ float4 xs[64];      // [k] x 4 samples
  __shared__ float4 hU[512];     // [unit] x 4 samples
  __shared__ float4 hV[512];
  __shared__ float4 pah[4][512]; // pairwise partials
  const int t = threadIdx.x;
  const int lane = t & 63, wv = t >> 6;
  const int b0 = blockIdx.x * 4;

  if (t < 256) {
    const int k2 = t >> 2, s2 = t & 3;  // 256 threads cover 4 samples x 64 k
    ((float*)&xs[k2])[s2] = x[(size_t)(b0 + s2) * 64 + k2];
  }
  __syncthreads();

  fwd_layer9<8>(W1Tf, b1, xs, hU, pah, m1p + (size_t)b0 * 16, t, lane, wv);
  fwd_layer9<64>(W2Tf, b2, hU, hV, pah, m2p + (size_t)b0 * 16, t, lane, wv);
  fwd_layer9<64>(W3Tf, b3, hV, hU, pah, m3p + (size_t)b0 * 16, t, lane, wv);

  // ---- layer 4 (K=512, D=64) + 0.5*||s||^2 : wave wv owns 64-k slice ----
  {
    const int d = lane;
    const int k0 = wv * 64;
    const float* Wb4 = W4Tf + (size_t)k0 * 64 + d;
    float a4[4] = {0.f, 0.f, 0.f, 0.f};
    float v0 = Wb4[(size_t)0 * 64], v1 = Wb4[(size_t)1 * 64];
    float v2 = Wb4[(size_t)2 * 64], v3 = Wb4[(size_t)3 * 64];
    float4 g0 = hU[k0 + 0], g1 = hU[k0 + 1], g2 = hU[k0 + 2], g3 = hU[k0 + 3];
#pragma unroll 1
    for (int kk = 0; kk < 64; kk += 4) {
      a4[0] = fmaf(v0, g0.x, a4[0]); a4[1] = fmaf(v0, g0.y, a4[1]);
      a4[2] = fmaf(v0, g0.z, a4[2]); a4[3] = fmaf(v0, g0.w, a4[3]);
      g0 = hU[k0 + kk + 4];
      v0 = Wb4[(size_t)(kk + 4) * 64];
      a4[0] = fmaf(v1, g1.x, a4[0]); a4[1] = fmaf(v1, g1.y, a4[1]);
      a4[2] = fmaf(v1, g1.z, a4[2]); a4[3] = fmaf(v1, g1.w, a4[3]);
      g1 = hU[k0 + kk + 5];
      v1 = Wb4[(size_t)(kk + 5) * 64];
      a4[0] = fmaf(v2, g2.x, a4[0]); a4[1] = fmaf(v2, g2.y, a4[1]);
      a4[2] = fmaf(v2, g2.z, a4[2]); a4[3] = fmaf(v2, g2.w, a4[3]);
      g2 = hU[k0 + kk + 6];
      v2 = Wb4[(size_t)(kk + 6) * 64];
      a4[0] = fmaf(v3, g3.x, a4[0]); a4[1] = fmaf(v3, g3.y, a4[1]);
      a4[2] = fmaf(v3, g3.z, a4[2]); a4[3] = fmaf(v3, g3.w, a4[3]);
      g3 = hU[k0 + kk + 7];
      v3 = Wb4[(size_t)(kk + 7) * 64];
    }
    const int half = wv >> 1;
    float4 pv;
    pv.x = a4[0]; pv.y = a4[1]; pv.z = a4[2]; pv.w = a4[3];
    if ((wv & 1) == 0) pah[half][d] = pv;
    __syncthreads();
    if (wv & 1) {
      float4 v = pah[half][d];
      v.x += pv.x; v.y += pv.y; v.z += pv.z; v.w += pv.w;
      pah[half][d] = v;
    }
    __syncthreads();
  }
  if (t < 64) {
    const float4 q0 = pah[0][t], q1 = pah[1][t], q2 = pah[2][t], q3 = pah[3][t];
    const float bj = b4[t];
    float sq[4];
    sq[0] = ((q0.x + q1.x) + (q2.x + q3.x)) + bj;
    sq[1] = ((q0.y + q1.y) + (q2.y + q3.y)) + bj;
    sq[2] = ((q0.z + q1.z) + (q2.z + q3.z)) + bj;
    sq[3] = ((q0.w + q1.w) + (q2.w + q3.w)) + bj;
#pragma unroll
    for (int s = 0; s < 4; ++s) sq[s] *= sq[s];
#pragma unroll
    for (int off = 32; off; off >>= 1) {
      sq[0] += __shfl_down(sq[0], off, 64);
      sq[1] += __shfl_down(sq[1], off, 64);
      sq[2] += __shfl_down(sq[2], off, 64);
      sq[3] += __shfl_down(sq[3], off, 64);
    }
    if (t == 0) {
      out[b0 + 0] = 0.5f * sq[0];
      out[b0 + 1] = 0.5f * sq[1];
      out[b0 + 2] = 0.5f * sq[2];
      out[b0 + 3] = 0.5f * sq[3];
    }
  }
}

// ---------------- divergence v5 (147us stable): C/G wave split, 4 waves/SIMD ----------------
// LAUNCHED AS 4 DISPATCHES (y0 = 0,2,4,6; grid (512,2)) so each dispatch is
// ~37us -> forward/convert visible in rocprof top-5. Work identical.
// grid (512 sample-quads, 2 row-tiles of 64); block 512 = 8 waves.
// Wave wv: sLoc = wv&3 -> sample g4*4+sLoc; role = (wv<4 ? C : G).
// Staging: per kc, block stages 16 slots (A2 it0-3 | u1 jt0-3 | A3 it0-3 |
// u4 jt0-3); wave wv stages slots wv*2, wv*2+1 (2 global_load_lds). 3 buffers,
// stage kc+2 at top of kc, end-of-kc s_waitcnt vmcnt(2) + raw s_barrier.
// Masks: expand_mask hoisted to LDS (emask); in-loop one broadcast b128 per kc.
// Epilogue: C-waves write accC to LDS (stride-65); G-waves apply m2, reduce.
__device__ __forceinline__ void expand_mask(uint32_t byte8, uint32_t mk[4]) {
#pragma unroll
  for (int i = 0; i < 4; ++i) {
    mk[i] = (((byte8 >> (2 * i)) & 1u) ? 0x0000FFFFu : 0u) |
            (((byte8 >> (2 * i + 1)) & 1u) ? 0xFFFF0000u : 0u);
  }
}

__global__ __launch_bounds__(512, 4) void div_kernel(
    const uint4* __restrict__ A2swz, const uint4* __restrict__ A3swz,
    const uint4* __restrict__ B1swz, const uint4* __restrict__ B4swz,
    const uint32_t* __restrict__ m1p, const uint32_t* __restrict__ m2p,
    const uint32_t* __restrict__ m3p, float* __restrict__ out, int y0) {
  __shared__ uint4 sfrag[3][16][64];   // 48KB: [buf][slot][lane]
  __shared__ uint4 emask[8][16][4];    // 8KB: [wave][kc][quad] expanded masks
  const int t = threadIdx.x;
  const int lane = t & 63, wv = t >> 6;
  const int quad = lane >> 4, l15 = lane & 15;
  const int g4 = blockIdx.x;
  const int yb = y0 + blockIdx.y;
  const int rowB0 = yb * 64;
  const int sLoc = wv & 3;
  const int b = g4 * 4 + sLoc;        // this wave's sample
  const int r16b = yb * 4;            // row-16-tile base
  const bool isC = (wv < 4);

  // staging source base for this wave's 2 slots
  const uint4* sb = (wv < 2) ? A2swz : (wv < 4) ? B1swz : (wv < 6) ? A3swz : B4swz;

  f32x4 acc[4][4];
#pragma unroll
  for (int it = 0; it < 4; ++it)
#pragma unroll
    for (int jt = 0; jt < 4; ++jt) acc[it][jt] = (f32x4){0.f, 0.f, 0.f, 0.f};

  // per-wave expanded-mask precompute: lane -> (kc = lane>>2, qd = lane&3).
  // C-waves use m1, G-waves use m3. Wave-private (in-wave lgkmcnt ordering).
  {
    const uint32_t* mp = (isC ? m1p : m3p) + (size_t)b * 16;
    const int kcl = lane >> 2, qd = lane & 3;
    const uint32_t word = mp[kcl];
    uint32_t mk[4];
    expand_mask((word >> (qd * 8)) & 0xFFu, mk);
    uint4 v;
    v.x = mk[0]; v.y = mk[1]; v.z = mk[2]; v.w = mk[3];
    emask[wv][kcl][qd] = v;
  }

  // stage(buf, kc): wave wv stages slots wv*2, wv*2+1
  auto stage = [&](int sbuf, int kc) {
#pragma unroll
    for (int q = 0; q < 2; ++q) {
      const int sub = (wv & 1) * 2 + q;  // it or jt index
      const size_t off = ((wv & 2) == 0)
          ? ((size_t)((r16b + sub) * 16 + kc) * 64 + lane)   // A2 / A3
          : ((size_t)(kc * 4 + sub) * 64 + lane);            // B1 / B4
      lds_load16(sb + off, &sfrag[sbuf][wv * 2 + q][0]);
    }
  };

  stage(0, 0);
  stage(1, 1);
  __builtin_amdgcn_sched_barrier(0);
  asm volatile("s_waitcnt vmcnt(2)" ::: "memory");  // kc=0 staging complete
  __builtin_amdgcn_s_barrier();
  __builtin_amdgcn_sched_barrier(0);

  const int base = isC ? 0 : 8;

#pragma unroll 1
  for (int kc = 0; kc < 16; ++kc) {
    const int rb = kc % 3;
    if (kc < 14) stage((kc + 2) % 3, kc + 2);  // keep 2 kc in flight

    const uint4 mku = emask[wv][kc][quad];  // broadcast ds_read_b128

    uint4 a[4], u[4];
#pragma unroll
    for (int q = 0; q < 4; ++q) {
      a[q] = sfrag[rb][base + q][lane];
      u[q] = sfrag[rb][base + 4 + q][lane];
    }

    short8 bf[4];
#pragma unroll
    for (int jt = 0; jt < 4; ++jt) {
      U16x8 uu;
      uu.u = u[jt];
      uu.u.x &= mku.x; uu.u.y &= mku.y; uu.u.z &= mku.z; uu.u.w &= mku.w;
      bf[jt] = uu.s;
    }
#pragma unroll
    for (int it = 0; it < 4; ++it) {
      U16x8 ua;
      ua.u = a[it];
      const short8 af = ua.s;
#pragma unroll
      for (int jt = 0; jt < 4; ++jt)
        acc[it][jt] = __builtin_amdgcn_mfma_f32_16x16x32_bf16(af, bf[jt], acc[it][jt], 0, 0, 0);
    }

    // counted wait: kc+1's staging (oldest 2) done; kc+2's 2 stay in flight.
    if (kc < 14) {
      asm volatile("s_waitcnt vmcnt(2)" ::: "memory");
    } else if (kc == 14) {
      asm volatile("s_waitcnt vmcnt(0)" ::: "memory");  // drain last stage
    }
    if (kc < 15) {
      __builtin_amdgcn_s_barrier();
      __builtin_amdgcn_sched_barrier(0);  // no ds_read hoisting above barrier
    }
  }

  // ---- epilogue: exchange C via LDS (2 halves of 32 rows), G applies m2 ----
  // C/D layout: row = it*16 + quad*4 + reg, col = jt*16 + l15.
  __syncthreads();  // all sfrag reads done; safe to overlay
  float* cxf = (float*)&sfrag[0][0][0];  // [sample][32 rows][stride 65]
  float dsum = 0.f;
  const uint32_t* m2w = m2p + (size_t)b * 16;
#pragma unroll
  for (int h = 0; h < 2; ++h) {
    if (isC) {
#pragma unroll
      for (int ith = 0; ith < 2; ++ith)
#pragma unroll
        for (int jt = 0; jt < 4; ++jt) {
          float* crow = &cxf[((size_t)sLoc * 32 + ith * 16 + quad * 4) * 65 +
                             jt * 16 + l15];
          crow[0 * 65] = acc[h * 2 + ith][jt][0];
          crow[1 * 65] = acc[h * 2 + ith][jt][1];
          crow[2 * 65] = acc[h * 2 + ith][jt][2];
          crow[3 * 65] = acc[h * 2 + ith][jt][3];
        }
    }
    __syncthreads();
    if (!isC) {
#pragma unroll
      for (int ith = 0; ith < 2; ++ith) {
        const int it = h * 2 + ith;
        const int rloc = it * 16 + quad * 4;
        const uint32_t md = m2w[(rowB0 + rloc) >> 5];
        const uint32_t bits = (md >> (rloc & 31)) & 0xFu;
        const float w0 = (bits & 1u) ? 1.f : 0.f;
        const float w1 = (bits & 2u) ? 1.f : 0.f;
        const float w2 = (bits & 4u) ? 1.f : 0.f;
        const float w3 = (bits & 8u) ? 1.f : 0.f;
#pragma unroll
        for (int jt = 0; jt < 4; ++jt) {
          const float* crow = &cxf[((size_t)sLoc * 32 + ith * 16 + quad * 4) * 65 +
                                   jt * 16 + l15];
          dsum = fmaf(w0, acc[it][jt][0] * crow[0 * 65], dsum);
          dsum = fmaf(w1, acc[it][jt][1] * crow[1 * 65], dsum);
          dsum = fmaf(w2, acc[it][jt][2] * crow[2 * 65], dsum);
          dsum = fmaf(w3, acc[it][jt][3] * crow[3 * 65], dsum);
        }
      }
    }
    __syncthreads();
  }
  if (!isC) {
#pragma unroll
    for (int off = 32; off; off >>= 1) dsum += __shfl_down(dsum, off, 64);
    if (lane == 0) atomicAdd(out + b, dsum);
  }
}

extern "C" void kernel_launch(void* const* d_in, const int* in_sizes, int n_in,
                              void* d_out, int out_size, void* d_ws, size_t ws_size,
                              hipStream_t stream) {
  const float* x  = (const float*)d_in[0];
  const float* W1 = (const float*)d_in[1];
  const float* b1 = (const float*)d_in[2];
  const float* W2 = (const float*)d_in[3];
  const float* b2 = (const float*)d_in[4];
  const float* W3 = (const float*)d_in[5];
  const float* b3 = (const float*)d_in[6];
  const float* W4 = (const float*)d_in[7];
  const float* b4 = (const float*)d_in[8];
  float* out = (float*)d_out;

  // workspace layout (bytes), total 3,932,160:
  char* ws = (char*)d_ws;
  uint16_t* A2swz = (uint16_t*)(ws + 0);        // 524288
  uint16_t* A3swz = (uint16_t*)(ws + 524288);   // 524288
  uint16_t* B1swz = (uint16_t*)(ws + 1048576);  // 65536
  uint16_t* B4swz = (uint16_t*)(ws + 1114112);  // 65536
  float*    W2Tf  = (float*)(ws + 1179648);     // 1048576
  float*    W3Tf  = (float*)(ws + 2228224);     // 1048576
  float*    W1Tf  = (float*)(ws + 3276800);     // 131072
  float*    W4Tf  = (float*)(ws + 3407872);     // 131072
  uint32_t* m1p   = (uint32_t*)(ws + 3538944);  // 131072 (2048 x 512 bits)
  uint32_t* m2p   = (uint32_t*)(ws + 3670016);  // 131072
  uint32_t* m3p   = (uint32_t*)(ws + 3801088);  // 131072
  if (ws_size < 3932160) return;

  convert_kernel<<<4608, 256, 0, stream>>>(W1, W2, W3, W4,
                                           A2swz, A3swz, B1swz, B4swz,
                                           W2Tf, W3Tf, W1Tf, W4Tf);
  forward_kernel<<<512, 512, 0, stream>>>(x, W1Tf, b1, W2Tf, b2, W3Tf, b3,
                                          W4Tf, b4, m1p, m2p, m3p, out);
  for (int y0 = 0; y0 < 8; y0 += 2) {
    div_kernel<<<dim3(512, 2), 512, 0, stream>>>((const uint4*)A2swz,
                                                 (const uint4*)A3swz,
                                                 (const uint4*)B1swz,
                                                 (const uint4*)B4swz,
                                                 m1p, m2p, m3p, out, y0);
  }
}

// Round 14
// 261.931 us; speedup vs baseline: 1.8201x; 1.0027x over previous
//
#include <hip/hip_runtime.h>
#include <stdint.h>

// ScoreMatching: B=2048, D=64, H=512.
// out[b] = 0.5*||s_b||^2 + tr(W4 M3 W3 M2 W2 M1 W1)_b
// div_b = sum_{i,d} m2[i] * C[i,d] * G[i,d]
//   C = W2 @ (M1 .* W1)      [512 x 64]   A-frag = W2 rows,  B-frag = W1T rows
//   G = W3^T @ (M3 .* W4^T)  [512 x 64]   A-frag = W3T rows, B-frag = W4 rows
// R18 changes:
//  - R13 confirmed: forward v10 is spill-free (WRITE_SIZE 733MB -> 400KB =
//    masks only) and runs 65us. The remaining 262-222 = ~40us was the
//    6-launch chain's inter-dispatch gaps (diagnostic div 4-way split).
//  - div: merged back to ONE dispatch, grid (512,8) -- the R10 config
//    measured at 147.0us. Kernel body identical.
//  - forward v10 / convert unchanged.

typedef __attribute__((ext_vector_type(8))) short short8;
typedef __attribute__((ext_vector_type(4))) float f32x4;

union U16x8 {
  uint4 u;
  short8 s;
};

__device__ __forceinline__ uint16_t f2bf(float f) {
  uint32_t u = __float_as_uint(f);
  uint32_t lsb = (u >> 16) & 1u;
  u += 0x7FFFu + lsb;  // round-to-nearest-even
  return (uint16_t)(u >> 16);
}

// async global->LDS, 16B per lane: lane's data lands at lds_base + lane*16.
__device__ __forceinline__ void lds_load16(const uint4* gsrc, uint4* ldst) {
  __builtin_amdgcn_global_load_lds(
      (const __attribute__((address_space(1))) void*)gsrc,
      (__attribute__((address_space(3))) void*)ldst, 16, 0, 0);
}

// ---------------- convert: build swizzled bf16 fragments + fp32 transposes ----------------
// Fragment order (16x16x32 bf16 MFMA): lane = quad*16 + l15 holds 8 contiguous
// bf16 = 16 B; A-frag element (m=l15, k=quad*8+j); B-frag (n=l15, k=quad*8+j).
// A2swz[((r16*16 + kc)*64 + lane)*8 + j] = W2 [r16*16+l15][kc*32+quad*8+j]
// A3swz[  same index                   ] = W3T[r16*16+l15][kc*32+quad*8+j]
// B1swz[((kc*4 + jt)*64 + lane)*8 + j]  = W1T[jt*16+l15 ][kc*32+quad*8+j]
// B4swz[  same index                 ]  = W4 [jt*16+l15 ][kc*32+quad*8+j]
__global__ __launch_bounds__(256) void convert_kernel(
    const float* __restrict__ W1, const float* __restrict__ W2,
    const float* __restrict__ W3, const float* __restrict__ W4,
    uint16_t* __restrict__ A2swz, uint16_t* __restrict__ A3swz,
    uint16_t* __restrict__ B1swz, uint16_t* __restrict__ B4swz,
    float* __restrict__ W2Tf, float* __restrict__ W3Tf,
    float* __restrict__ W1Tf, float* __restrict__ W4Tf) {
  const int i = blockIdx.x * 256 + threadIdx.x;
  if (i < 262144) {  // A2swz
    const int e = i;
    const int f = e >> 3, j = e & 7;
    const int lane = f & 63, fk = f >> 6;
    const int kc = fk & 15, r16 = fk >> 4;
    const int l15 = lane & 15, quad = lane >> 4;
    const int row = r16 * 16 + l15, col = kc * 32 + quad * 8 + j;
    A2swz[e] = f2bf(W2[row * 512 + col]);
  } else if (i < 524288) {  // A3swz (= W3 transposed)
    const int e = i - 262144;
    const int f = e >> 3, j = e & 7;
    const int lane = f & 63, fk = f >> 6;
    const int kc = fk & 15, r16 = fk >> 4;
    const int l15 = lane & 15, quad = lane >> 4;
    const int row = r16 * 16 + l15, col = kc * 32 + quad * 8 + j;
    A3swz[e] = f2bf(W3[col * 512 + row]);
  } else if (i < 557056) {  // B1swz (= W1 transposed)
    const int e = i - 524288;
    const int f = e >> 3, j = e & 7;
    const int lane = f & 63, fk = f >> 6;
    const int kc = fk >> 2, jt = fk & 3;
    const int l15 = lane & 15, quad = lane >> 4;
    const int d = jt * 16 + l15, col = kc * 32 + quad * 8 + j;
    B1swz[e] = f2bf(W1[col * 64 + d]);
  } else if (i < 589824) {  // B4swz (= W4 row-major)
    const int e = i - 557056;
    const int f = e >> 3, j = e & 7;
    const int lane = f & 63, fk = f >> 6;
    const int kc = fk >> 2, jt = fk & 3;
    const int l15 = lane & 15, quad = lane >> 4;
    const int d = jt * 16 + l15, col = kc * 32 + quad * 8 + j;
    B4swz[e] = f2bf(W4[d * 512 + col]);
  } else if (i < 851968) {  // W2Tf [k][j]
    const int e = i - 589824;
    const int k = e >> 9, jj = e & 511;
    W2Tf[e] = W2[jj * 512 + k];
  } else if (i < 1114112) {  // W3Tf [k][j]
    const int e = i - 851968;
    const int k = e >> 9, jj = e & 511;
    W3Tf[e] = W3[jj * 512 + k];
  } else if (i < 1146880) {  // W1Tf [k][j], k<64
    const int e = i - 1114112;
    const int k = e >> 9, jj = e & 511;
    W1Tf[e] = W1[jj * 64 + k];
  } else if (i < 1179648) {  // W4Tf [k][d]
    const int e = i - 1146880;
    const int k = e >> 6, d = e & 63;
    W4Tf[e] = W4[d * 512 + k];
  }
}

// ---------------- forward v10 (fp32): K-sliced waves, spill-free reg budget ----------------
// 512 blocks x 512 threads (8 waves); block = 4 samples; amdgpu_waves_per_eu
// (4,4) pins a 128-VGPR budget (no spill; R12's launch_bounds(512,4) gave a
// 64-reg budget and 733MB spill). Wave wv owns k-slice [wv*KPW,(wv+1)*KPW).
// Thread owns units {lane+64p} x 4 samples. Per k: 1 broadcast b128 + 8
// coalesced w-loads + 32 FMA; 4-deep named W/h rotation.
__device__ __forceinline__ void fma8x4(float acc[8][4], const float w[8],
                                       const float4 h) {
#pragma unroll
  for (int p = 0; p < 8; ++p) {
    acc[p][0] = fmaf(w[p], h.x, acc[p][0]);
    acc[p][1] = fmaf(w[p], h.y, acc[p][1]);
    acc[p][2] = fmaf(w[p], h.z, acc[p][2]);
    acc[p][3] = fmaf(w[p], h.w, acc[p][3]);
  }
}

template <int KPW>
__device__ __forceinline__ void fwd_layer9(
    const float* __restrict__ WT, const float* __restrict__ bias,
    const float4* __restrict__ src, float4* __restrict__ dst,
    float4 (* __restrict__ pah)[512], uint32_t* __restrict__ mbase,
    int t, int lane, int wv) {
  float acc[8][4];
#pragma unroll
  for (int p = 0; p < 8; ++p)
#pragma unroll
    for (int s = 0; s < 4; ++s) acc[p][s] = 0.f;

  const int k0 = wv * KPW;
  const float* Wb = WT + (size_t)k0 * 512 + lane;
  float w0[8], w1[8], w2[8], w3[8];
#pragma unroll
  for (int p = 0; p < 8; ++p) {
    w0[p] = Wb[(size_t)0 * 512 + p * 64];
    w1[p] = Wb[(size_t)1 * 512 + p * 64];
    w2[p] = Wb[(size_t)2 * 512 + p * 64];
    w3[p] = Wb[(size_t)3 * 512 + p * 64];
  }
  float4 h0 = src[k0 + 0], h1 = src[k0 + 1], h2 = src[k0 + 2], h3 = src[k0 + 3];

#pragma unroll 1
  for (int kk = 0; kk < KPW; kk += 4) {
    // buffer q: FMA, then immediately issue its reload for kk+4+q
    // (final iteration over-reads into adjacent workspace/LDS; values unused)
    fma8x4(acc, w0, h0);
    h0 = src[k0 + kk + 4];
#pragma unroll
    for (int p = 0; p < 8; ++p) w0[p] = Wb[(size_t)(kk + 4) * 512 + p * 64];
    fma8x4(acc, w1, h1);
    h1 = src[k0 + kk + 5];
#pragma unroll
    for (int p = 0; p < 8; ++p) w1[p] = Wb[(size_t)(kk + 5) * 512 + p * 64];
    fma8x4(acc, w2, h2);
    h2 = src[k0 + kk + 6];
#pragma unroll
    for (int p = 0; p < 8; ++p) w2[p] = Wb[(size_t)(kk + 6) * 512 + p * 64];
    fma8x4(acc, w3, h3);
    h3 = src[k0 + kk + 7];
#pragma unroll
    for (int p = 0; p < 8; ++p) w3[p] = Wb[(size_t)(kk + 7) * 512 + p * 64];
  }

  // pairwise partial combine: even waves write, odd waves add (deterministic)
  const int half = wv >> 1;
  if ((wv & 1) == 0) {
#pragma unroll
    for (int p = 0; p < 8; ++p) {
      float4 v;
      v.x = acc[p][0]; v.y = acc[p][1]; v.z = acc[p][2]; v.w = acc[p][3];
      pah[half][p * 64 + lane] = v;
    }
  }
  __syncthreads();
  if (wv & 1) {
#pragma unroll
    for (int p = 0; p < 8; ++p) {
      float4 v = pah[half][p * 64 + lane];
      v.x += acc[p][0]; v.y += acc[p][1]; v.z += acc[p][2]; v.w += acc[p][3];
      pah[half][p * 64 + lane] = v;
    }
  }
  __syncthreads();

  // combine pass: unit u = t
  {
    const int u = t;
    const float4 a0 = pah[0][u], a1 = pah[1][u], a2 = pah[2][u], a3 = pah[3][u];
    const float bj = bias[u];
    float a[4];
    a[0] = ((a0.x + a1.x) + (a2.x + a3.x)) + bj;
    a[1] = ((a0.y + a1.y) + (a2.y + a3.y)) + bj;
    a[2] = ((a0.z + a1.z) + (a2.z + a3.z)) + bj;
    a[3] = ((a0.w + a1.w) + (a2.w + a3.w)) + bj;
#pragma unroll
    for (int s = 0; s < 4; ++s) {
      const unsigned long long bal = __ballot(a[s] > 0.f);
      if (lane == 0) {
        uint2 w2v;
        w2v.x = (uint32_t)bal;
        w2v.y = (uint32_t)(bal >> 32);
        *(uint2*)(mbase + (size_t)s * 16 + 2 * wv) = w2v;
      }
    }
    float4 r;
    r.x = a[0] > 0.f ? a[0] : 0.f;
    r.y = a[1] > 0.f ? a[1] : 0.f;
    r.z = a[2] > 0.f ? a[2] : 0.f;
    r.w = a[3] > 0.f ? a[3] : 0.f;
    dst[u] = r;
  }
  __syncthreads();
}

__global__ __launch_bounds__(512)
__attribute__((amdgpu_waves_per_eu(4, 4)))
void forward_kernel(
    const float* __restrict__ x,
    const float* __restrict__ W1Tf, const float* __restrict__ b1,
    const float* __restrict__ W2Tf, const float* __restrict__ b2,
    const float* __restrict__ W3Tf, const float* __restrict__ b3,
    const float* __restrict__ W4Tf, const float* __restrict__ b4,
    uint32_t* __restrict__ m1p, uint32_t* __restrict__ m2p,
    uint32_t* __restrict__ m3p, float* __restrict__ out) {
  // pah declared LAST so k-loop over-prefetch from xs/hU/hV stays in-bounds
  __shared__ float4 xs[64];      // [k] x 4 samples
  __shared__ float4 hU[512];     // [unit] x 4 samples
  __shared__ float4 hV[512];
  __shared__ float4 pah[4][512]; // pairwise partials
  const int t = threadIdx.x;
  const int lane = t & 63, wv = t >> 6;
  const int b0 = blockIdx.x * 4;

  if (t < 256) {
    const int k2 = t >> 2, s2 = t & 3;  // 256 threads cover 4 samples x 64 k
    ((float*)&xs[k2])[s2] = x[(size_t)(b0 + s2) * 64 + k2];
  }
  __syncthreads();

  fwd_layer9<8>(W1Tf, b1, xs, hU, pah, m1p + (size_t)b0 * 16, t, lane, wv);
  fwd_layer9<64>(W2Tf, b2, hU, hV, pah, m2p + (size_t)b0 * 16, t, lane, wv);
  fwd_layer9<64>(W3Tf, b3, hV, hU, pah, m3p + (size_t)b0 * 16, t, lane, wv);

  // ---- layer 4 (K=512, D=64) + 0.5*||s||^2 : wave wv owns 64-k slice ----
  {
    const int d = lane;
    const int k0 = wv * 64;
    const float* Wb4 = W4Tf + (size_t)k0 * 64 + d;
    float a4[4] = {0.f, 0.f, 0.f, 0.f};
    float v0 = Wb4[(size_t)0 * 64], v1 = Wb4[(size_t)1 * 64];
    float v2 = Wb4[(size_t)2 * 64], v3 = Wb4[(size_t)3 * 64];
    float4 g0 = hU[k0 + 0], g1 = hU[k0 + 1], g2 = hU[k0 + 2], g3 = hU[k0 + 3];
#pragma unroll 1
    for (int kk = 0; kk < 64; kk += 4) {
      a4[0] = fmaf(v0, g0.x, a4[0]); a4[1] = fmaf(v0, g0.y, a4[1]);
      a4[2] = fmaf(v0, g0.z, a4[2]); a4[3] = fmaf(v0, g0.w, a4[3]);
      g0 = hU[k0 + kk + 4];
      v0 = Wb4[(size_t)(kk + 4) * 64];
      a4[0] = fmaf(v1, g1.x, a4[0]); a4[1] = fmaf(v1, g1.y, a4[1]);
      a4[2] = fmaf(v1, g1.z, a4[2]); a4[3] = fmaf(v1, g1.w, a4[3]);
      g1 = hU[k0 + kk + 5];
      v1 = Wb4[(size_t)(kk + 5) * 64];
      a4[0] = fmaf(v2, g2.x, a4[0]); a4[1] = fmaf(v2, g2.y, a4[1]);
      a4[2] = fmaf(v2, g2.z, a4[2]); a4[3] = fmaf(v2, g2.w, a4[3]);
      g2 = hU[k0 + kk + 6];
      v2 = Wb4[(size_t)(kk + 6) * 64];
      a4[0] = fmaf(v3, g3.x, a4[0]); a4[1] = fmaf(v3, g3.y, a4[1]);
      a4[2] = fmaf(v3, g3.z, a4[2]); a4[3] = fmaf(v3, g3.w, a4[3]);
      g3 = hU[k0 + kk + 7];
      v3 = Wb4[(size_t)(kk + 7) * 64];
    }
    const int half = wv >> 1;
    float4 pv;
    pv.x = a4[0]; pv.y = a4[1]; pv.z = a4[2]; pv.w = a4[3];
    if ((wv & 1) == 0) pah[half][d] = pv;
    __syncthreads();
    if (wv & 1) {
      float4 v = pah[half][d];
      v.x += pv.x; v.y += pv.y; v.z += pv.z; v.w += pv.w;
      pah[half][d] = v;
    }
    __syncthreads();
  }
  if (t < 64) {
    const float4 q0 = pah[0][t], q1 = pah[1][t], q2 = pah[2][t], q3 = pah[3][t];
    const float bj = b4[t];
    float sq[4];
    sq[0] = ((q0.x + q1.x) + (q2.x + q3.x)) + bj;
    sq[1] = ((q0.y + q1.y) + (q2.y + q3.y)) + bj;
    sq[2] = ((q0.z + q1.z) + (q2.z + q3.z)) + bj;
    sq[3] = ((q0.w + q1.w) + (q2.w + q3.w)) + bj;
#pragma unroll
    for (int s = 0; s < 4; ++s) sq[s] *= sq[s];
#pragma unroll
    for (int off = 32; off; off >>= 1) {
      sq[0] += __shfl_down(sq[0], off, 64);
      sq[1] += __shfl_down(sq[1], off, 64);
      sq[2] += __shfl_down(sq[2], off, 64);
      sq[3] += __shfl_down(sq[3], off, 64);
    }
    if (t == 0) {
      out[b0 + 0] = 0.5f * sq[0];
      out[b0 + 1] = 0.5f * sq[1];
      out[b0 + 2] = 0.5f * sq[2];
      out[b0 + 3] = 0.5f * sq[3];
    }
  }
}

// ---------------- divergence v5 (147us stable): C/G wave split, 4 waves/SIMD ----------------
// Single dispatch, grid (512 sample-quads, 8 row-tiles of 64); block 512 = 8 waves.
// Wave wv: sLoc = wv&3 -> sample g4*4+sLoc; role = (wv<4 ? C : G).
// Staging: per kc, block stages 16 slots (A2 it0-3 | u1 jt0-3 | A3 it0-3 |
// u4 jt0-3); wave wv stages slots wv*2, wv*2+1 (2 global_load_lds). 3 buffers,
// stage kc+2 at top of kc, end-of-kc s_waitcnt vmcnt(2) + raw s_barrier.
// Masks: expand_mask hoisted to LDS (emask); in-loop one broadcast b128 per kc.
// Epilogue: C-waves write accC to LDS (stride-65); G-waves apply m2, reduce.
__device__ __forceinline__ void expand_mask(uint32_t byte8, uint32_t mk[4]) {
#pragma unroll
  for (int i = 0; i < 4; ++i) {
    mk[i] = (((byte8 >> (2 * i)) & 1u) ? 0x0000FFFFu : 0u) |
            (((byte8 >> (2 * i + 1)) & 1u) ? 0xFFFF0000u : 0u);
  }
}

__global__ __launch_bounds__(512, 4) void div_kernel(
    const uint4* __restrict__ A2swz, const uint4* __restrict__ A3swz,
    const uint4* __restrict__ B1swz, const uint4* __restrict__ B4swz,
    const uint32_t* __restrict__ m1p, const uint32_t* __restrict__ m2p,
    const uint32_t* __restrict__ m3p, float* __restrict__ out) {
  __shared__ uint4 sfrag[3][16][64];   // 48KB: [buf][slot][lane]
  __shared__ uint4 emask[8][16][4];    // 8KB: [wave][kc][quad] expanded masks
  const int t = threadIdx.x;
  const int lane = t & 63, wv = t >> 6;
  const int quad = lane >> 4, l15 = lane & 15;
  const int g4 = blockIdx.x;
  const int yb = blockIdx.y;
  const int rowB0 = yb * 64;
  const int sLoc = wv & 3;
  const int b = g4 * 4 + sLoc;        // this wave's sample
  const int r16b = yb * 4;            // row-16-tile base
  const bool isC = (wv < 4);

  // staging source base for this wave's 2 slots
  const uint4* sb = (wv < 2) ? A2swz : (wv < 4) ? B1swz : (wv < 6) ? A3swz : B4swz;

  f32x4 acc[4][4];
#pragma unroll
  for (int it = 0; it < 4; ++it)
#pragma unroll
    for (int jt = 0; jt < 4; ++jt) acc[it][jt] = (f32x4){0.f, 0.f, 0.f, 0.f};

  // per-wave expanded-mask precompute: lane -> (kc = lane>>2, qd = lane&3).
  // C-waves use m1, G-waves use m3. Wave-private (in-wave lgkmcnt ordering).
  {
    const uint32_t* mp = (isC ? m1p : m3p) + (size_t)b * 16;
    const int kcl = lane >> 2, qd = lane & 3;
    const uint32_t word = mp[kcl];
    uint32_t mk[4];
    expand_mask((word >> (qd * 8)) & 0xFFu, mk);
    uint4 v;
    v.x = mk[0]; v.y = mk[1]; v.z = mk[2]; v.w = mk[3];
    emask[wv][kcl][qd] = v;
  }

  // stage(buf, kc): wave wv stages slots wv*2, wv*2+1
  auto stage = [&](int sbuf, int kc) {
#pragma unroll
    for (int q = 0; q < 2; ++q) {
      const int sub = (wv & 1) * 2 + q;  // it or jt index
      const size_t off = ((wv & 2) == 0)
          ? ((size_t)((r16b + sub) * 16 + kc) * 64 + lane)   // A2 / A3
          : ((size_t)(kc * 4 + sub) * 64 + lane);            // B1 / B4
      lds_load16(sb + off, &sfrag[sbuf][wv * 2 + q][0]);
    }
  };

  stage(0, 0);
  stage(1, 1);
  __builtin_amdgcn_sched_barrier(0);
  asm volatile("s_waitcnt vmcnt(2)" ::: "memory");  // kc=0 staging complete
  __builtin_amdgcn_s_barrier();
  __builtin_amdgcn_sched_barrier(0);

  const int base = isC ? 0 : 8;

#pragma unroll 1
  for (int kc = 0; kc < 16; ++kc) {
    const int rb = kc % 3;
    if (kc < 14) stage((kc + 2) % 3, kc + 2);  // keep 2 kc in flight

    const uint4 mku = emask[wv][kc][quad];  // broadcast ds_read_b128

    uint4 a[4], u[4];
#pragma unroll
    for (int q = 0; q < 4; ++q) {
      a[q] = sfrag[rb][base + q][lane];
      u[q] = sfrag[rb][base + 4 + q][lane];
    }

    short8 bf[4];
#pragma unroll
    for (int jt = 0; jt < 4; ++jt) {
      U16x8 uu;
      uu.u = u[jt];
      uu.u.x &= mku.x; uu.u.y &= mku.y; uu.u.z &= mku.z; uu.u.w &= mku.w;
      bf[jt] = uu.s;
    }
#pragma unroll
    for (int it = 0; it < 4; ++it) {
      U16x8 ua;
      ua.u = a[it];
      const short8 af = ua.s;
#pragma unroll
      for (int jt = 0; jt < 4; ++jt)
        acc[it][jt] = __builtin_amdgcn_mfma_f32_16x16x32_bf16(af, bf[jt], acc[it][jt], 0, 0, 0);
    }

    // counted wait: kc+1's staging (oldest 2) done; kc+2's 2 stay in flight.
    if (kc < 14) {
      asm volatile("s_waitcnt vmcnt(2)" ::: "memory");
    } else if (kc == 14) {
      asm volatile("s_waitcnt vmcnt(0)" ::: "memory");  // drain last stage
    }
    if (kc < 15) {
      __builtin_amdgcn_s_barrier();
      __builtin_amdgcn_sched_barrier(0);  // no ds_read hoisting above barrier
    }
  }

  // ---- epilogue: exchange C via LDS (2 halves of 32 rows), G applies m2 ----
  // C/D layout: row = it*16 + quad*4 + reg, col = jt*16 + l15.
  __syncthreads();  // all sfrag reads done; safe to overlay
  float* cxf = (float*)&sfrag[0][0][0];  // [sample][32 rows][stride 65]
  float dsum = 0.f;
  const uint32_t* m2w = m2p + (size_t)b * 16;
#pragma unroll
  for (int h = 0; h < 2; ++h) {
    if (isC) {
#pragma unroll
      for (int ith = 0; ith < 2; ++ith)
#pragma unroll
        for (int jt = 0; jt < 4; ++jt) {
          float* crow = &cxf[((size_t)sLoc * 32 + ith * 16 + quad * 4) * 65 +
                             jt * 16 + l15];
          crow[0 * 65] = acc[h * 2 + ith][jt][0];
          crow[1 * 65] = acc[h * 2 + ith][jt][1];
          crow[2 * 65] = acc[h * 2 + ith][jt][2];
          crow[3 * 65] = acc[h * 2 + ith][jt][3];
        }
    }
    __syncthreads();
    if (!isC) {
#pragma unroll
      for (int ith = 0; ith < 2; ++ith) {
        const int it = h * 2 + ith;
        const int rloc = it * 16 + quad * 4;
        const uint32_t md = m2w[(rowB0 + rloc) >> 5];
        const uint32_t bits = (md >> (rloc & 31)) & 0xFu;
        const float w0 = (bits & 1u) ? 1.f : 0.f;
        const float w1 = (bits & 2u) ? 1.f : 0.f;
        const float w2 = (bits & 4u) ? 1.f : 0.f;
        const float w3 = (bits & 8u) ? 1.f : 0.f;
#pragma unroll
        for (int jt = 0; jt < 4; ++jt) {
          const float* crow = &cxf[((size_t)sLoc * 32 + ith * 16 + quad * 4) * 65 +
                                   jt * 16 + l15];
          dsum = fmaf(w0, acc[it][jt][0] * crow[0 * 65], dsum);
          dsum = fmaf(w1, acc[it][jt][1] * crow[1 * 65], dsum);
          dsum = fmaf(w2, acc[it][jt][2] * crow[2 * 65], dsum);
          dsum = fmaf(w3, acc[it][jt][3] * crow[3 * 65], dsum);
        }
      }
    }
    __syncthreads();
  }
  if (!isC) {
#pragma unroll
    for (int off = 32; off; off >>= 1) dsum += __shfl_down(dsum, off, 64);
    if (lane == 0) atomicAdd(out + b, dsum);
  }
}

extern "C" void kernel_launch(void* const* d_in, const int* in_sizes, int n_in,
                              void* d_out, int out_size, void* d_ws, size_t ws_size,
                              hipStream_t stream) {
  const float* x  = (const float*)d_in[0];
  const float* W1 = (const float*)d_in[1];
  const float* b1 = (const float*)d_in[2];
  const float* W2 = (const float*)d_in[3];
  const float* b2 = (const float*)d_in[4];
  const float* W3 = (const float*)d_in[5];
  const float* b3 = (const float*)d_in[6];
  const float* W4 = (const float*)d_in[7];
  const float* b4 = (const float*)d_in[8];
  float* out = (float*)d_out;

  // workspace layout (bytes), total 3,932,160:
  char* ws = (char*)d_ws;
  uint16_t* A2swz = (uint16_t*)(ws + 0);        // 524288
  uint16_t* A3swz = (uint16_t*)(ws + 524288);   // 524288
  uint16_t* B1swz = (uint16_t*)(ws + 1048576);  // 65536
  uint16_t* B4swz = (uint16_t*)(ws + 1114112);  // 65536
  float*    W2Tf  = (float*)(ws + 1179648);     // 1048576
  float*    W3Tf  = (float*)(ws + 2228224);     // 1048576
  float*    W1Tf  = (float*)(ws + 3276800);     // 131072
  float*    W4Tf  = (float*)(ws + 3407872);     // 131072
  uint32_t* m1p   = (uint32_t*)(ws + 3538944);  // 131072 (2048 x 512 bits)
  uint32_t* m2p   = (uint32_t*)(ws + 3670016);  // 131072
  uint32_t* m3p   = (uint32_t*)(ws + 3801088);  // 131072
  if (ws_size < 3932160) return;

  convert_kernel<<<4608, 256, 0, stream>>>(W1, W2, W3, W4,
                                           A2swz, A3swz, B1swz, B4swz,
                                           W2Tf, W3Tf, W1Tf, W4Tf);
  forward_kernel<<<512, 512, 0, stream>>>(x, W1Tf, b1, W2Tf, b2, W3Tf, b3,
                                          W4Tf, b4, m1p, m2p, m3p, out);
  div_kernel<<<dim3(512, 8), 512, 0, stream>>>((const uint4*)A2swz,
                                               (const uint4*)A3swz,
                                               (const uint4*)B1swz,
                                               (const uint4*)B4swz,
                                               m1p, m2p, m3p, out);
}